// Round 2
// baseline (62.188 us; speedup 1.0000x reference)
//
#include <hip/hip_runtime.h>

#define B_ 2
#define C_ 121
#define H_ 128
#define W_ 256
#define D_ 48
#define CT 11        // channels per LDS chunk
#define NCHUNK 11    // 121 = 11 * 11
#define NT 384       // 64 w-quads * 6 d-groups
#define NDY 8        // disparities per thread
#define YROW 312     // padded y row (need 304), multiple of 4

typedef const void __attribute__((address_space(1)))* gas1_t;
typedef void __attribute__((address_space(3)))* las3_t;

__launch_bounds__(NT)
__global__ void cost_volume_kernel(const float* __restrict__ xg,
                                   const float* __restrict__ yg,
                                   float* __restrict__ out)
{
    // x rows: [chunk-channel][w 0..255]
    // y rows: [chunk-channel][p], p = (w') + 48, w' in [-48, 256); p<48 is zero pad
    __shared__ __align__(16) float XLS[2][CT][W_];
    __shared__ __align__(16) float YLS[2][CT][YROW];

    const int t    = threadIdx.x;
    const int h    = blockIdx.x;
    const int b    = blockIdx.y;
    const int wq   = t & 63;        // w-quad: w = wq*4 .. wq*4+3
    const int wv   = t >> 6;        // wave id == d-group, 0..5
    const int d0   = wv * NDY;      // d = d0 .. d0+7  (d0 multiple of 8 -> mod 4 == 0)
    const int lane = wq;

    // zero the left pad (p in [0,48)) of every y row, both buffers, once.
    for (int i = t; i < 2 * CT * 48; i += NT) {
        int nb = i / (CT * 48);
        int r  = i % (CT * 48);
        YLS[nb][r / 48][r % 48] = 0.0f;
    }

    // stage one chunk (11 channels x {x row, y row}) directly global->LDS.
    auto stage = [&](int chunk, int nb) {
        for (int i = wv; i < 2 * CT; i += 6) {   // wave-uniform loop
            const int cc = i >> 1;
            const int c  = chunk * CT + cc;
            const size_t row = (((size_t)b * C_ + c) * H_ + h) * (size_t)W_;
            if (i & 1) {
                const float* g = yg + row + (size_t)lane * 4;
                __builtin_amdgcn_global_load_lds((gas1_t)g, (las3_t)&YLS[nb][cc][48], 16, 0, 0);
            } else {
                const float* g = xg + row + (size_t)lane * 4;
                __builtin_amdgcn_global_load_lds((gas1_t)g, (las3_t)&XLS[nb][cc][0], 16, 0, 0);
            }
        }
    };

    float acc[NDY][4];
    #pragma unroll
    for (int jd = 0; jd < NDY; ++jd)
        #pragma unroll
        for (int jw = 0; jw < 4; ++jw) acc[jd][jw] = 0.0f;

    stage(0, 0);
    __syncthreads();

    for (int k = 0; k < NCHUNK; ++k) {
        const int cur = k & 1;
        if (k + 1 < NCHUNK) stage(k + 1, cur ^ 1);   // prefetch next chunk (lands by barrier)

        #pragma unroll
        for (int cc = 0; cc < CT; ++cc) {
            // x fragment: 4 consecutive w, 16B aligned
            const float4 xv = *(const float4*)&XLS[cur][cc][wq * 4];
            const float xvv[4] = {xv.x, xv.y, xv.z, xv.w};

            // y window: p_needed = w - d + 48 spans [wq*4-d0+41, wq*4-d0+51];
            // base = wq*4-d0+40 is 0 mod 4 for every lane -> 3 aligned b128 reads.
            const int bp = wq * 4 - d0 + 40;
            float yw[12];
            *(float4*)&yw[0] = *(const float4*)&YLS[cur][cc][bp];
            *(float4*)&yw[4] = *(const float4*)&YLS[cur][cc][bp + 4];
            *(float4*)&yw[8] = *(const float4*)&YLS[cur][cc][bp + 8];

            #pragma unroll
            for (int jd = 0; jd < NDY; ++jd)
                #pragma unroll
                for (int jw = 0; jw < 4; ++jw)
                    acc[jd][jw] += __builtin_fabsf(xvv[jw] - yw[8 + jw - jd]);

            // prefix boundaries: c+1 = k^2, k = 3..11. Constant-folds to scalar k==const.
            #pragma unroll
            for (int bi = 0; bi < 9; ++bi) {
                constexpr int KB[9] = {8, 15, 24, 35, 48, 63, 80, 99, 120};
                const int bc = KB[bi];
                if (k * CT + cc == bc) {
                    const float inv = 1.0f / (float)(bc + 1);
                    const size_t obase = (((size_t)b * 9 + bi) * D_) * (size_t)(H_ * W_)
                                       + (size_t)h * W_ + (size_t)wq * 4;
                    #pragma unroll
                    for (int jd = 0; jd < NDY; ++jd) {
                        const int d = d0 + jd;
                        float4 v;
                        v.x = (wq * 4 + 0 >= d) ? acc[jd][0] * inv : 0.0f;
                        v.y = (wq * 4 + 1 >= d) ? acc[jd][1] * inv : 0.0f;
                        v.z = (wq * 4 + 2 >= d) ? acc[jd][2] * inv : 0.0f;
                        v.w = (wq * 4 + 3 >= d) ? acc[jd][3] * inv : 0.0f;
                        *(float4*)&out[obase + (size_t)d * (H_ * W_)] = v;
                    }
                }
            }
        }
        __syncthreads();
    }
}

extern "C" void kernel_launch(void* const* d_in, const int* in_sizes, int n_in,
                              void* d_out, int out_size, void* d_ws, size_t ws_size,
                              hipStream_t stream)
{
    const float* x = (const float*)d_in[0];
    const float* y = (const float*)d_in[1];
    float* o = (float*)d_out;
    dim3 grid(H_, B_, 1);
    dim3 block(NT, 1, 1);
    hipLaunchKernelGGL(cost_volume_kernel, grid, block, 0, stream, x, y, o);
}

// Round 3
// 50.174 us; speedup vs baseline: 1.2394x; 1.2394x over previous
//
#include <hip/hip_runtime.h>

#define B_ 2
#define C_ 121
#define H_ 128
#define W_ 256
#define D_ 48
#define CT 11        // channels per LDS chunk
#define NCHUNK 11    // 121 = 11 * 11
#define NT 256       // 4 waves: 64 w-quads x 4 d-groups
#define NDY 4        // disparities per thread
#define YROW 312     // padded y row (need 304), multiple of 4
#define ZS 3         // disparity split: 16 d per block

typedef const void __attribute__((address_space(1)))* gas1_t;
typedef void __attribute__((address_space(3)))* las3_t;

__launch_bounds__(NT)
__global__ void cost_volume_kernel(const float* __restrict__ xg,
                                   const float* __restrict__ yg,
                                   float* __restrict__ out)
{
    // x rows: [chunk-channel][w 0..255]
    // y rows: [chunk-channel][p], p = w' + 48, w' in [-48, 256); p<48 zero pad
    __shared__ __align__(16) float XLS[2][CT][W_];
    __shared__ __align__(16) float YLS[2][CT][YROW];

    const int t  = threadIdx.x;
    const int h  = blockIdx.x;
    const int b  = blockIdx.y;
    const int z  = blockIdx.z;      // d-split: this block owns d in [z*16, z*16+16)
    const int wq = t & 63;          // w-quad: w = wq*4 .. wq*4+3
    const int wv = t >> 6;          // wave id = d-group within block, 0..3
    const int d0 = z * 16 + wv * NDY;   // multiple of 4

    // zero the left pad (p in [0,48)) of every y row, both buffers, once.
    for (int i = t; i < 2 * CT * 48; i += NT) {
        int nb = i / (CT * 48);
        int r  = i % (CT * 48);
        YLS[nb][r / 48][r % 48] = 0.0f;
    }

    // stage one chunk (11 channels x {x row, y row}) directly global->LDS.
    auto stage = [&](int chunk, int nb) {
        for (int i = wv; i < 2 * CT; i += 4) {   // wave-uniform loop
            const int cc = i >> 1;
            const int c  = chunk * CT + cc;
            const size_t row = (((size_t)b * C_ + c) * H_ + h) * (size_t)W_;
            if (i & 1) {
                __builtin_amdgcn_global_load_lds((gas1_t)(yg + row + (size_t)wq * 4),
                                                 (las3_t)&YLS[nb][cc][48], 16, 0, 0);
            } else {
                __builtin_amdgcn_global_load_lds((gas1_t)(xg + row + (size_t)wq * 4),
                                                 (las3_t)&XLS[nb][cc][0], 16, 0, 0);
            }
        }
    };

    float acc[NDY][4];
    #pragma unroll
    for (int jd = 0; jd < NDY; ++jd)
        #pragma unroll
        for (int jw = 0; jw < 4; ++jw) acc[jd][jw] = 0.0f;

    stage(0, 0);
    __syncthreads();

    for (int k = 0; k < NCHUNK; ++k) {
        const int cur = k & 1;
        if (k + 1 < NCHUNK) stage(k + 1, cur ^ 1);   // prefetch next chunk

        #pragma unroll
        for (int cc = 0; cc < CT; ++cc) {
            // x fragment: 4 consecutive w, 16B aligned
            const float4 xv = *(const float4*)&XLS[cur][cc][wq * 4];
            const float xvv[4] = {xv.x, xv.y, xv.z, xv.w};

            // y window: needed p = w - d + 48 spans [bp+1, bp+7],
            // bp = wq*4 - d0 + 44 is a multiple of 4 (min 0, max+7 = 303).
            const int bp = wq * 4 - d0 + 44;
            float yw[8];
            *(float4*)&yw[0] = *(const float4*)&YLS[cur][cc][bp];
            *(float4*)&yw[4] = *(const float4*)&YLS[cur][cc][bp + 4];

            #pragma unroll
            for (int jd = 0; jd < NDY; ++jd)
                #pragma unroll
                for (int jw = 0; jw < 4; ++jw)
                    acc[jd][jw] += __builtin_fabsf(xvv[jw] - yw[4 + jw - jd]);

            // prefix boundaries: c+1 = k^2, k = 3..11 (scalar compile-time compares)
            #pragma unroll
            for (int bi = 0; bi < 9; ++bi) {
                constexpr int KB[9] = {8, 15, 24, 35, 48, 63, 80, 99, 120};
                const int bc = KB[bi];
                if (k * CT + cc == bc) {
                    const float inv = 1.0f / (float)(bc + 1);
                    const size_t obase = (((size_t)b * 9 + bi) * D_) * (size_t)(H_ * W_)
                                       + (size_t)h * W_ + (size_t)wq * 4;
                    #pragma unroll
                    for (int jd = 0; jd < NDY; ++jd) {
                        const int d = d0 + jd;
                        float4 v;
                        v.x = (wq * 4 + 0 >= d) ? acc[jd][0] * inv : 0.0f;
                        v.y = (wq * 4 + 1 >= d) ? acc[jd][1] * inv : 0.0f;
                        v.z = (wq * 4 + 2 >= d) ? acc[jd][2] * inv : 0.0f;
                        v.w = (wq * 4 + 3 >= d) ? acc[jd][3] * inv : 0.0f;
                        *(float4*)&out[obase + (size_t)d * (H_ * W_)] = v;
                    }
                }
            }
        }
        __syncthreads();
    }
}

extern "C" void kernel_launch(void* const* d_in, const int* in_sizes, int n_in,
                              void* d_out, int out_size, void* d_ws, size_t ws_size,
                              hipStream_t stream)
{
    const float* x = (const float*)d_in[0];
    const float* y = (const float*)d_in[1];
    float* o = (float*)d_out;
    dim3 grid(H_, B_, ZS);   // z slowest: d-split siblings are 256 ids apart
    dim3 block(NT, 1, 1);
    hipLaunchKernelGGL(cost_volume_kernel, grid, block, 0, stream, x, y, o);
}